// Round 4
// baseline (1242.535 us; speedup 1.0000x reference)
//
#include <hip/hip_runtime.h>
#include <hip/hip_bf16.h>

typedef __bf16  bf16x8 __attribute__((ext_vector_type(8)));
typedef float   f32x4  __attribute__((ext_vector_type(4)));

// global->LDS async, 16B/lane.
// _C: fully cached (read-only X stream). _H: sc0 = bypass L1, allocate in L2
// (h panels; freshness guaranteed by the per-phase acquire fence -> buffer_inv).
#define GLOAD16_C(gptr, lptr) \
  __builtin_amdgcn_global_load_lds((const __attribute__((address_space(1))) void*)(gptr), \
                                   (__attribute__((address_space(3))) void*)(lptr), 16, 0, 0)
#define GLOAD16_H(gptr, lptr) \
  __builtin_amdgcn_global_load_lds((const __attribute__((address_space(1))) void*)(gptr), \
                                   (__attribute__((address_space(3))) void*)(lptr), 16, 0, 0x1)

#define WAIT_VM4   asm volatile("s_waitcnt vmcnt(4)" ::: "memory")
#define WAIT_VM2   asm volatile("s_waitcnt vmcnt(2)" ::: "memory")
#define WAIT_VM0   asm volatile("s_waitcnt vmcnt(0)" ::: "memory")
#define WAIT_LGKM0 asm volatile("s_waitcnt lgkmcnt(0)" ::: "memory")

__device__ __forceinline__ float sigm(float x)  { return 1.0f / (1.0f + __expf(-x)); }
__device__ __forceinline__ float tanhp(float x) { return 2.0f / (1.0f + __expf(-2.0f * x)) - 1.0f; }

// coherent (LLC) scalar load, bypasses L1/L2
__device__ __forceinline__ unsigned int coh_load(const unsigned int* p) {
  unsigned int v;
  asm volatile("global_load_dword %0, %1, off sc0 sc1\n\ts_waitcnt vmcnt(0)"
               : "=v"(v) : "v"(p) : "memory");
  return v;
}
// coherent bf16 store (write-through to LLC; no dirty L2 lines anywhere)
__device__ __forceinline__ void coh_store_bf16(__hip_bfloat16* p, float x) {
  __hip_bfloat16 hv = __float2bfloat16(x);
  unsigned int b = (unsigned int)*(unsigned short*)&hv;
  asm volatile("global_store_short %0, %1, off sc0 sc1" :: "v"(p), "v"(b) : "memory");
}

#define TSTEPS 80
#define BATCH  512
#define EDIM   256
#define HDIM   512
#define K2     1024
#define K1     768
// LDS: Bs chunk-major swizzled (64 x K bf16, no pad) + 3-deep A ring (8 KB each)
#define LDS_BYTES (64 * K2 * 2 + 3 * 8192)

struct Params {
  const __hip_bfloat16* Wz1t;   // [2048][768]  bf16, [N'][K], col-permuted
  const __hip_bfloat16* Wz2t;   // [2048][1024]
  const float* bz1;             // [2048] permuted
  const float* bz2;
  const __hip_bfloat16* Xall;   // [80][512][256] bf16
  __hip_bfloat16* h1b0; __hip_bfloat16* h1b1;   // [512][512] bf16 ping-pong
  __hip_bfloat16* h2b0; __hip_bfloat16* h2b1;
  unsigned int* cnt;            // 4 group barrier counters, 128B apart
  const float* Wfc; const float* bfc;
  float* out;
};

// ---------------- prep kernels ----------------
// permuted column: n' = ntile*64 + gate*16 + u  (ntile = j>>4, u = j&15)

__global__ __launch_bounds__(256) void prep_weights(
    const float* __restrict__ W1, const float* __restrict__ U1, const float* __restrict__ b1,
    const float* __restrict__ W2, const float* __restrict__ U2, const float* __restrict__ b2,
    __hip_bfloat16* __restrict__ Wz1t, __hip_bfloat16* __restrict__ Wz2t,
    float* __restrict__ bz1, float* __restrict__ bz2) {
  long idx = (long)blockIdx.x * 256 + threadIdx.x;
  const long n1 = 2048L * K1, n2 = 2048L * K2;
  if (idx < n1) {
    int n = (int)(idx / K1), k = (int)(idx % K1);
    int col = ((n >> 4) & 3) * 512 + (n >> 6) * 16 + (n & 15);
    float v = (k < 512) ? U1[(size_t)k * 2048 + col] : W1[(size_t)(k - 512) * 2048 + col];
    Wz1t[idx] = __float2bfloat16(v);
  } else if (idx < n1 + n2) {
    long r = idx - n1;
    int n = (int)(r / K2), k = (int)(r % K2);
    int col = ((n >> 4) & 3) * 512 + (n >> 6) * 16 + (n & 15);
    float v = (k < 512) ? W2[(size_t)k * 2048 + col] : U2[(size_t)(k - 512) * 2048 + col];
    Wz2t[r] = __float2bfloat16(v);
  } else if (idx < n1 + n2 + 2048) {
    int n = (int)(idx - (n1 + n2));
    bz1[n] = b1[((n >> 4) & 3) * 512 + (n >> 6) * 16 + (n & 15)];
  } else if (idx < n1 + n2 + 4096) {
    int n = (int)(idx - (n1 + n2 + 2048));
    bz2[n] = b2[((n >> 4) & 3) * 512 + (n >> 6) * 16 + (n & 15)];
  }
}

__global__ __launch_bounds__(256) void prep_gather(
    const int* __restrict__ tokens, const float* __restrict__ emb,
    __hip_bfloat16* __restrict__ Xall) {
  int idx = blockIdx.x * 256 + threadIdx.x;
  int e  = (idx & 63) * 4;
  int rb = idx >> 6;            // t*512 + b
  int t  = rb >> 9;
  int b  = rb & 511;
  int tok = tokens[b * TSTEPS + t];
  const float4 v = *(const float4*)&emb[(size_t)tok * EDIM + e];
  __hip_bfloat16* o = Xall + (size_t)rb * EDIM + e;
  o[0] = __float2bfloat16(v.x); o[1] = __float2bfloat16(v.y);
  o[2] = __float2bfloat16(v.z); o[3] = __float2bfloat16(v.w);
}

__global__ __launch_bounds__(256) void zero_ws(float4* p, int n) {
  int i = blockIdx.x * 256 + threadIdx.x;
  if (i < n) p[i] = make_float4(0.f, 0.f, 0.f, 0.f);
}

// ---------------- main sequential kernel ----------------
// 256 blocks x 256 threads, 1 block/CU. Block b: group g=(b>>1)&3 (m-rows
// g*128..), role z2 if (b&1)==0, ntile = b>>3. blockIdx%8 = 2g+role => each
// (group,role) set of 32 blocks owns one XCD: its A-panel re-reads are
// L2-local after a single LLC fill. h stores are write-through (sc0 sc1);
// per-phase acquire fence (buffer_inv) makes L2 h-lines fresh. Barriers are
// per-group 64-block atomic counters in LLC.

__global__ __launch_bounds__(256) void lstm_seq(Params p) {
  extern __shared__ char smem[];
  const int tid  = threadIdx.x;
  const int lane = tid & 63;
  const int w    = tid >> 6;
  const int q    = lane >> 4;
  const int m16  = lane & 15;

  const int  grp   = (blockIdx.x >> 1) & 3;
  const bool z2    = ((blockIdx.x & 1) == 0);
  const int  ntile = blockIdx.x >> 3;          // 0..31
  const int  m0    = grp * 128;
  const int  n0    = ntile * 64;
  const int  K  = z2 ? K2 : K1;
  const int  nc = K / 32;
  unsigned int* cnt = p.cnt + grp * 32;

  __hip_bfloat16* Bs   = (__hip_bfloat16*)smem;                       // chunk-major swizzled
  __hip_bfloat16* ring = (__hip_bfloat16*)(smem + (size_t)64 * K * 2);

  // one-time: persistent B tile into LDS, chunk-major granule-swizzled:
  // granule (row r, colgroup c8) of chunk kc lands at
  //   Bs + kc*2048 + r*32 + (c8 ^ ((r>>1)&3))*8     (elems)
  const __hip_bfloat16* Bg = (z2 ? p.Wz2t : p.Wz1t) + (size_t)n0 * K;
  for (int idx = tid; idx < 64 * (K / 8); idx += 256) {
    int r  = idx / (K / 8);
    int cg = idx - r * (K / 8);
    int kc = cg >> 2, c8 = cg & 3;
    int sw = c8 ^ ((r >> 1) & 3);
    *(bf16x8*)(Bs + kc * 2048 + r * 32 + sw * 8) =
        *(const bf16x8*)(Bg + (size_t)r * K + kc * 32 + c8 * 8);
  }
  const float* bias = z2 ? p.bz2 : p.bz1;
  float bz[4];
#pragma unroll
  for (int g = 0; g < 4; ++g) bz[g] = bias[n0 + g * 16 + m16];

  float cst[2][4] = {{0.f,0.f,0.f,0.f},{0.f,0.f,0.f,0.f}};   // cell state in regs
  __syncthreads();

  for (int ph = -1; ph < TSTEPS; ++ph) {
    if (z2 ? (ph >= 0) : (ph < TSTEPS - 1)) {
      const __hip_bfloat16* A0 = (ph & 1) ? p.h1b1 : p.h1b0;     // h1[ph]
      const __hip_bfloat16* A1;
      if (z2) A1 = ((ph + 1) & 1) ? p.h2b1 : p.h2b0;             // h2[ph-1]
      else    A1 = p.Xall + (size_t)(ph + 1) * BATCH * EDIM;     // x[ph+1]

      auto stage = [&](int kc) {
        const int slot = kc % 3;
        const int kk = kc * 32;
#pragma unroll
        for (int it = 0; it < 2; ++it) {
          const int gbase = w * 128 + it * 64;
          const int g   = gbase + lane;
          const int row = g >> 2;
          const int gc  = (g & 3) ^ ((row >> 1) & 3);     // XOR swizzle
          __hip_bfloat16* lp = ring + (size_t)slot * 4096 + gbase * 8;
          if (kk < 512) {
            GLOAD16_H(A0 + (size_t)(m0 + row) * 512 + kk + gc * 8, lp);
          } else if (z2) {
            GLOAD16_H(A1 + (size_t)(m0 + row) * 512 + (kk - 512) + gc * 8, lp);
          } else {
            GLOAD16_C(A1 + (size_t)(m0 + row) * 256 + (kk - 512) + gc * 8, lp);
          }
        }
      };

      f32x4 acc[2][4];
#pragma unroll
      for (int mi = 0; mi < 2; ++mi)
#pragma unroll
        for (int g = 0; g < 4; ++g)
          acc[mi][g] = (f32x4){bz[g], bz[g], bz[g], bz[g]};

      WAIT_LGKM0;                     // prior-phase ds_reads retired before restage
      stage(0); stage(1); stage(2);

      const int rb2 = (m16 >> 1) & 3;
      const int laneB = m16 * 32 + (q ^ rb2) * 8;      // B frag offset within chunk

      for (int kc = 0; kc < nc; ++kc) {
        if      (kc <= nc - 3) WAIT_VM4;
        else if (kc == nc - 2) WAIT_VM2;
        else                   WAIT_VM0;
        const int slot = kc % 3;
        bf16x8 af[2], bfr[4];
#pragma unroll
        for (int mi = 0; mi < 2; ++mi) {
          const int row = w * 32 + mi * 16 + m16;
          const int sw  = q ^ ((row >> 1) & 3);
          af[mi] = *(const bf16x8*)(ring + slot * 4096 + row * 32 + sw * 8);
        }
#pragma unroll
        for (int g = 0; g < 4; ++g)
          bfr[g] = *(const bf16x8*)(Bs + kc * 2048 + g * 512 + laneB);
        WAIT_LGKM0;                   // frags in regs; ring slot kc%3 free
        if (kc + 3 < nc) stage(kc + 3);
#pragma unroll
        for (int mi = 0; mi < 2; ++mi)
#pragma unroll
          for (int g = 0; g < 4; ++g)
            acc[mi][g] = __builtin_amdgcn_mfma_f32_16x16x32_bf16(af[mi], bfr[g], acc[mi][g], 0, 0, 0);
      }

      // in-register epilogue; coherent h stores
      __hip_bfloat16* hout = z2 ? ((ph & 1) ? p.h2b1 : p.h2b0)            // h2[ph]
                                : (((ph + 1) & 1) ? p.h1b1 : p.h1b0);     // h1[ph+1]
      const int j = ntile * 16 + m16;
#pragma unroll
      for (int mi = 0; mi < 2; ++mi)
#pragma unroll
        for (int rr = 0; rr < 4; ++rr) {
          const float zi = acc[mi][0][rr], zf = acc[mi][1][rr];
          const float zg = acc[mi][2][rr], zo = acc[mi][3][rr];
          const float cn = sigm(zf) * cst[mi][rr] + sigm(zi) * tanhp(zg);
          cst[mi][rr] = cn;
          const int row = m0 + w * 32 + mi * 16 + q * 4 + rr;
          coh_store_bf16(hout + (size_t)row * HDIM + j, sigm(zo) * tanhp(cn));
        }
    }

    // ---- per-group barrier + L2 invalidate (acquire) ----
    WAIT_VM0;                         // h stores committed to LLC
    __syncthreads();
    if (tid == 0) {
      const unsigned int tgt = 64u * (unsigned)(ph + 2);
      if (atomicAdd(cnt, 1u) + 1u < tgt)
        while (coh_load(cnt) < tgt) __builtin_amdgcn_s_sleep(1);
      __builtin_amdgcn_fence(__ATOMIC_ACQUIRE, "agent");   // buffer_inv: drop stale L2 h-lines
    }
    __syncthreads();                  // orders all waves' loads after the inv
  }

  // final FC: block b -> rows {2b, 2b+1}; wait on producer group's counter
  if (tid == 0) {
    unsigned int* pc = p.cnt + (blockIdx.x >> 6) * 32;
    while (coh_load(pc) < 64u * 81u) __builtin_amdgcn_s_sleep(1);
  }
  __syncthreads();
  if (w < 2) {
    const int row = blockIdx.x * 2 + w;
    const unsigned int* hp = (const unsigned int*)(p.h2b1 + (size_t)row * HDIM);
    float sum = 0.f;
#pragma unroll
    for (int c = 0; c < 4; ++c) {
      unsigned int d = coh_load(hp + lane * 4 + c);
      union { unsigned int ui; float f; } lo, hi;
      lo.ui = d << 16; hi.ui = d & 0xffff0000u;
      sum += lo.f * p.Wfc[(lane * 4 + c) * 2] + hi.f * p.Wfc[(lane * 4 + c) * 2 + 1];
    }
#pragma unroll
    for (int o = 32; o > 0; o >>= 1) sum += __shfl_down(sum, o, 64);
    if (lane == 0) p.out[row] = sigm(sum + p.bfc[0]);
  }
}

// ---------------- host launcher ----------------

extern "C" void kernel_launch(void* const* d_in, const int* in_sizes, int n_in,
                              void* d_out, int out_size, void* d_ws, size_t ws_size,
                              hipStream_t stream) {
  const int*   tokens = (const int*)d_in[0];
  const float* emb = (const float*)d_in[1];
  const float* W1  = (const float*)d_in[2];
  const float* U1  = (const float*)d_in[3];
  const float* b1  = (const float*)d_in[4];
  const float* W2  = (const float*)d_in[5];
  const float* U2  = (const float*)d_in[6];
  const float* b2  = (const float*)d_in[7];
  const float* Wfc = (const float*)d_in[8];
  const float* bfc = (const float*)d_in[9];

  char* ws = (char*)d_ws;
  size_t off = 0;
  auto alloc = [&](size_t bytes) {
    char* r = ws + off;
    off += (bytes + 255) & ~(size_t)255;
    return r;
  };
  __hip_bfloat16* Wz1t = (__hip_bfloat16*)alloc(2048UL * K1 * 2);
  __hip_bfloat16* Wz2t = (__hip_bfloat16*)alloc(2048UL * K2 * 2);
  float* bz1 = (float*)alloc(2048 * 4);
  float* bz2 = (float*)alloc(2048 * 4);
  __hip_bfloat16* Xall = (__hip_bfloat16*)alloc((size_t)TSTEPS * BATCH * EDIM * 2);
  char* state = alloc(2UL * 1024 * 1024 + 4096);   // 4 h-buffers + counters, zeroed
  __hip_bfloat16* h1b0 = (__hip_bfloat16*)(state);
  __hip_bfloat16* h1b1 = (__hip_bfloat16*)(state + 512 * 1024);
  __hip_bfloat16* h2b0 = (__hip_bfloat16*)(state + 1024 * 1024);
  __hip_bfloat16* h2b1 = (__hip_bfloat16*)(state + 1536 * 1024);
  unsigned int*   cnt  = (unsigned int*)(state + 2048 * 1024);

  prep_weights<<<dim3(14352), dim3(256), 0, stream>>>(W1, U1, b1, W2, U2, b2, Wz1t, Wz2t, bz1, bz2);
  prep_gather<<<dim3(10240), dim3(256), 0, stream>>>(tokens, emb, Xall);
  zero_ws<<<dim3(516), dim3(256), 0, stream>>>((float4*)state, 131328);

  hipFuncSetAttribute((const void*)lstm_seq,
                      hipFuncAttributeMaxDynamicSharedMemorySize, LDS_BYTES);

  Params prm;
  prm.Wz1t = Wz1t; prm.Wz2t = Wz2t; prm.bz1 = bz1; prm.bz2 = bz2;
  prm.Xall = Xall;
  prm.h1b0 = h1b0; prm.h1b1 = h1b1; prm.h2b0 = h2b0; prm.h2b1 = h2b1;
  prm.cnt = cnt;
  prm.Wfc = Wfc; prm.bfc = bfc;
  prm.out = (float*)d_out;

  void* args[] = {&prm};
  hipLaunchCooperativeKernel((const void*)lstm_seq, dim3(256), dim3(256), args, LDS_BYTES, stream);
}

// Round 6
// 1034.471 us; speedup vs baseline: 1.2011x; 1.2011x over previous
//
#include <hip/hip_runtime.h>
#include <hip/hip_bf16.h>

typedef __bf16  bf16x8 __attribute__((ext_vector_type(8)));
typedef float   f32x4  __attribute__((ext_vector_type(4)));

// global->LDS async, 16B/lane. _C: fully cached (immutable streams).
// _H: sc0 = bypass L1, allocate L2 (h panels; per-phase acquire fence -> inv).
#define GLOAD16_C(gptr, lptr) \
  __builtin_amdgcn_global_load_lds((const __attribute__((address_space(1))) void*)(gptr), \
                                   (__attribute__((address_space(3))) void*)(lptr), 16, 0, 0)
#define GLOAD16_H(gptr, lptr) \
  __builtin_amdgcn_global_load_lds((const __attribute__((address_space(1))) void*)(gptr), \
                                   (__attribute__((address_space(3))) void*)(lptr), 16, 0, 0x1)

#define WAIT_VM10  asm volatile("s_waitcnt vmcnt(10)" ::: "memory")
#define WAIT_VM8   asm volatile("s_waitcnt vmcnt(8)"  ::: "memory")
#define WAIT_VM6   asm volatile("s_waitcnt vmcnt(6)"  ::: "memory")
#define WAIT_VM4   asm volatile("s_waitcnt vmcnt(4)"  ::: "memory")
#define WAIT_VM2   asm volatile("s_waitcnt vmcnt(2)"  ::: "memory")
#define WAIT_VM0   asm volatile("s_waitcnt vmcnt(0)"  ::: "memory")
#define WAIT_LGKM0 asm volatile("s_waitcnt lgkmcnt(0)" ::: "memory")

__device__ __forceinline__ float sigm(float x)  { return 1.0f / (1.0f + __expf(-x)); }
__device__ __forceinline__ float tanhp(float x) { return 2.0f / (1.0f + __expf(-2.0f * x)) - 1.0f; }

// LLC-coherent scalar load / stores (bypass L1/L2)
__device__ __forceinline__ unsigned int coh_load(const unsigned int* p) {
  unsigned int v;
  asm volatile("global_load_dword %0, %1, off sc0 sc1\n\ts_waitcnt vmcnt(0)"
               : "=v"(v) : "v"(p) : "memory");
  return v;
}
__device__ __forceinline__ int coh_load_i(const int* p) {
  int v;
  asm volatile("global_load_dword %0, %1, off sc0 sc1\n\ts_waitcnt vmcnt(0)"
               : "=v"(v) : "v"(p) : "memory");
  return v;
}
__device__ __forceinline__ void coh_store16(void* p, bf16x8 v) {
  f32x4 f = *(f32x4*)&v;
  asm volatile("global_store_dwordx4 %0, %1, off sc0 sc1" :: "v"(p), "v"(f) : "memory");
}
__device__ __forceinline__ void flag_store(int* fp, int v) {
  asm volatile("global_store_dword %0, %1, off sc0 sc1" :: "v"(fp), "v"(v) : "memory");
}

#define TSTEPS 80
#define BATCH  512
#define EDIM   256
#define HDIM   512
#define K2     1024
#define K1     768
#define NCH    8          // B K-chunks held in registers (128 VGPR)
// LDS: BsL (<=24 chunks * 4KB) | ring (6 * 8KB) | epi (128 x 24 bf16)
#define RING_OFF 98304
#define EPI_OFF  147456
#define EPI_STR  24
#define LDS_BYTES 153600

struct Params {
  const __hip_bfloat16* Wz1t;   // [2048][768]  bf16, [N'][K], col-permuted
  const __hip_bfloat16* Wz2t;   // [2048][1024]
  const float* bz1;             // [2048] permuted
  const float* bz2;
  const __hip_bfloat16* Xall;   // [80][512][256] bf16
  __hip_bfloat16* h1b[3];       // h1 triple buffer [512][512]
  __hip_bfloat16* h2b[2];       // h2 double buffer
  int* flags;                   // 256 entries, 16B stride: z1 at idx, z2 at 128+idx
  const float* Wfc; const float* bfc;
  float* out;
};

// ---------------- prep kernels (unchanged, proven) ----------------
// permuted column: n' = ntile*64 + gate*16 + u  (ntile = j>>4, u = j&15)

__global__ __launch_bounds__(256) void prep_weights(
    const float* __restrict__ W1, const float* __restrict__ U1, const float* __restrict__ b1,
    const float* __restrict__ W2, const float* __restrict__ U2, const float* __restrict__ b2,
    __hip_bfloat16* __restrict__ Wz1t, __hip_bfloat16* __restrict__ Wz2t,
    float* __restrict__ bz1, float* __restrict__ bz2) {
  long idx = (long)blockIdx.x * 256 + threadIdx.x;
  const long n1 = 2048L * K1, n2 = 2048L * K2;
  if (idx < n1) {
    int n = (int)(idx / K1), k = (int)(idx % K1);
    int col = ((n >> 4) & 3) * 512 + (n >> 6) * 16 + (n & 15);
    float v = (k < 512) ? U1[(size_t)k * 2048 + col] : W1[(size_t)(k - 512) * 2048 + col];
    Wz1t[idx] = __float2bfloat16(v);
  } else if (idx < n1 + n2) {
    long r = idx - n1;
    int n = (int)(r / K2), k = (int)(r % K2);
    int col = ((n >> 4) & 3) * 512 + (n >> 6) * 16 + (n & 15);
    float v = (k < 512) ? W2[(size_t)k * 2048 + col] : U2[(size_t)(k - 512) * 2048 + col];
    Wz2t[r] = __float2bfloat16(v);
  } else if (idx < n1 + n2 + 2048) {
    int n = (int)(idx - (n1 + n2));
    bz1[n] = b1[((n >> 4) & 3) * 512 + (n >> 6) * 16 + (n & 15)];
  } else if (idx < n1 + n2 + 4096) {
    int n = (int)(idx - (n1 + n2 + 2048));
    bz2[n] = b2[((n >> 4) & 3) * 512 + (n >> 6) * 16 + (n & 15)];
  }
}

__global__ __launch_bounds__(256) void prep_gather(
    const int* __restrict__ tokens, const float* __restrict__ emb,
    __hip_bfloat16* __restrict__ Xall) {
  int idx = blockIdx.x * 256 + threadIdx.x;
  int e  = (idx & 63) * 4;
  int rb = idx >> 6;            // t*512 + b
  int t  = rb >> 9;
  int b  = rb & 511;
  int tok = tokens[b * TSTEPS + t];
  const float4 v = *(const float4*)&emb[(size_t)tok * EDIM + e];
  __hip_bfloat16* o = Xall + (size_t)rb * EDIM + e;
  o[0] = __float2bfloat16(v.x); o[1] = __float2bfloat16(v.y);
  o[2] = __float2bfloat16(v.z); o[3] = __float2bfloat16(v.w);
}

__global__ __launch_bounds__(256) void zero_ws(float4* p, int n) {
  int i = blockIdx.x * 256 + threadIdx.x;
  if (i < n) p[i] = make_float4(0.f, 0.f, 0.f, 0.f);
}

// ---------------- main kernel ----------------
// 256 blocks x 256 threads, 1 block/CU (LDS-bound), REGULAR launch (flags
// make grid.sync unnecessary; 256 blocks @ 1/CU are co-resident, proven
// R2-R4). Block b: role z2 if (b&1)==0, grp=(b>>1)&3 (rows grp*128..),
// ntile=b>>3; blockIdx%8 = 2*grp+role pins each 32-block set to one XCD.
// Sync: per-block phase flags (write-through LLC); consumers poll 32 flags
// with ONE wave-parallel sc0sc1 load + ballot. z1 runs up to 2 phases ahead
// (h1 triple-buffered) so steady-state polls are pre-satisfied.

// wave0: lanes 0..31 poll z1 flags >= t1; lanes 32..63 poll z2 flags >= t2.
__device__ __forceinline__ void gate_wave(const int* flags, int base1, int t1,
                                          int base2, int t2, int lane) {
  const int idx = lane & 31;
  const int* fp = flags + (((lane < 32) ? base1 : base2) + idx) * 4;   // 16B stride
  const int tgt = (lane < 32) ? t1 : t2;
  for (;;) {
    int v = coh_load_i(fp);
    if (__ballot(v >= tgt) == ~0ull) break;
    __builtin_amdgcn_s_sleep(4);
  }
}

template<bool Z2>
__device__ __forceinline__ void role_loop(const Params& p, char* smem, int tid,
                                          int grp, int ntile) {
  constexpr int K  = Z2 ? K2 : K1;
  constexpr int NC = K / 32;
  const int lane = tid & 63;
  const int w    = tid >> 6;
  const int q    = lane >> 4;
  const int m16  = lane & 15;
  const int m0   = grp * 128;
  const int n0   = ntile * 64;

  __hip_bfloat16* BsL  = (__hip_bfloat16*)smem;
  __hip_bfloat16* ring = (__hip_bfloat16*)(smem + RING_OFF);
  __hip_bfloat16* epi  = (__hip_bfloat16*)(smem + EPI_OFF);

  const __hip_bfloat16* Bg = (Z2 ? p.Wz2t : p.Wz1t) + (size_t)n0 * K;

  // one-time: B chunks 0..NCH-1 into registers (static indexing only)
  bf16x8 breg[NCH][4];
#pragma unroll
  for (int kc = 0; kc < NCH; ++kc)
#pragma unroll
    for (int g = 0; g < 4; ++g)
      breg[kc][g] = *(const bf16x8*)(Bg + (size_t)(g * 16 + m16) * K + kc * 32 + q * 8);

  // one-time: B chunks NCH..NC-1 into LDS, chunk-major granule-swizzled
  for (int it0 = tid; it0 < (NC - NCH) * 256; it0 += 256) {
    int cid = it0 >> 8, gg = it0 & 255;
    int r = gg >> 2, c8 = gg & 3;
    int sw = c8 ^ ((r >> 1) & 3);
    *(bf16x8*)(BsL + cid * 2048 + r * 32 + sw * 8) =
        *(const bf16x8*)(Bg + (size_t)r * K + (NCH + cid) * 32 + c8 * 8);
  }
  const float* bias = Z2 ? p.bz2 : p.bz1;
  float bz[4];
#pragma unroll
  for (int g = 0; g < 4; ++g) bz[g] = bias[n0 + g * 16 + m16];

  const int swz = (q ^ ((m16 >> 1) & 3)) * 8;
  int aoff[2], boff[4];
#pragma unroll
  for (int mi = 0; mi < 2; ++mi) aoff[mi] = (w * 32 + mi * 16 + m16) * 32 + swz;
#pragma unroll
  for (int g = 0; g < 4; ++g)    boff[g]  = (g * 16 + m16) * 32 + swz;

  float cst[2][4] = {{0.f,0.f,0.f,0.f},{0.f,0.f,0.f,0.f}};
  const int fself = (Z2 ? 128 : 0) + grp * 32 + ntile;
  const int jbase = ntile * 16;
  __syncthreads();

  for (int s = 0; s < TSTEPS; ++s) {
    const __hip_bfloat16 *A0, *A1;
    if (Z2) { A0 = p.h1b[s % 3];       A1 = p.h2b[(s + 1) & 1]; }   // h1[s], h2[s-1]
    else    { A0 = p.h1b[(s + 2) % 3]; A1 = p.Xall + (size_t)s * BATCH * EDIM; } // h1[s-1], x[s]
    __hip_bfloat16* hout = Z2 ? p.h2b[s & 1] : p.h1b[s % 3];

    // dependency gate (wave0 polls; pre-satisfied in steady state)
    if (w == 0) {
      if (Z2) gate_wave(p.flags, grp * 32, s + 1, 128 + grp * 32, s, lane);
      else    gate_wave(p.flags, grp * 32, s,     128 + grp * 32, s - 2, lane);
      __builtin_amdgcn_fence(__ATOMIC_ACQUIRE, "agent");   // inv stale L2 h-lines
    }
    __syncthreads();

    // stage chunk kc: wave w loads its own 32 rows (2 insts)
    auto stage = [&](int kc) {
      const int slot = kc % 6;
      const int kk = kc * 32;
#pragma unroll
      for (int it = 0; it < 2; ++it) {
        const int gbase = w * 128 + it * 64;
        const int g   = gbase + lane;
        const int row = g >> 2;
        const int gc  = (g & 3) ^ ((row >> 1) & 3);       // XOR swizzle
        __hip_bfloat16* lp = ring + slot * 4096 + gbase * 8;
        if (kk < 512)  GLOAD16_H(A0 + (size_t)(m0 + row) * 512 + kk + gc * 8, lp);
        else if (Z2)   GLOAD16_H(A1 + (size_t)(m0 + row) * 512 + (kk - 512) + gc * 8, lp);
        else           GLOAD16_C(A1 + (size_t)(m0 + row) * 256 + (kk - 512) + gc * 8, lp);
      }
    };

    f32x4 acc[2][4];
#pragma unroll
    for (int mi = 0; mi < 2; ++mi)
#pragma unroll
      for (int g = 0; g < 4; ++g)
        acc[mi][g] = (f32x4){bz[g], bz[g], bz[g], bz[g]};

#pragma unroll
    for (int k0 = 0; k0 < 6; ++k0) stage(k0);

    // head: kc = 0..NCH-1 unrolled (breg static indexing); 6 chunks in flight
#pragma unroll
    for (int kc = 0; kc < NCH; ++kc) {
      WAIT_VM10;                                   // chunk kc resident
      const int slot = kc % 6;
      bf16x8 af[2];
#pragma unroll
      for (int mi = 0; mi < 2; ++mi)
        af[mi] = *(const bf16x8*)(ring + slot * 4096 + aoff[mi]);
      WAIT_LGKM0;
      stage(kc + 6);                               // kc+6 <= 13 < NC always
#pragma unroll
      for (int mi = 0; mi < 2; ++mi)
#pragma unroll
        for (int g = 0; g < 4; ++g)
          acc[mi][g] = __builtin_amdgcn_mfma_f32_16x16x32_bf16(af[mi], breg[kc][g], acc[mi][g], 0, 0, 0);
    }
    // tail: kc = NCH..NC-1, B from LDS
    for (int kc = NCH; kc < NC; ++kc) {
      const int rem = NC - 1 - kc;
      if      (rem >= 5) WAIT_VM10;
      else if (rem == 4) WAIT_VM8;
      else if (rem == 3) WAIT_VM6;
      else if (rem == 2) WAIT_VM4;
      else if (rem == 1) WAIT_VM2;
      else               WAIT_VM0;
      const int slot = kc % 6;
      bf16x8 af[2], bfr[4];
#pragma unroll
      for (int mi = 0; mi < 2; ++mi)
        af[mi] = *(const bf16x8*)(ring + slot * 4096 + aoff[mi]);
#pragma unroll
      for (int g = 0; g < 4; ++g)
        bfr[g] = *(const bf16x8*)(BsL + (kc - NCH) * 2048 + boff[g]);
      WAIT_LGKM0;
      if (kc + 6 < NC) stage(kc + 6);
#pragma unroll
      for (int mi = 0; mi < 2; ++mi)
#pragma unroll
        for (int g = 0; g < 4; ++g)
          acc[mi][g] = __builtin_amdgcn_mfma_f32_16x16x32_bf16(af[mi], bfr[g], acc[mi][g], 0, 0, 0);
    }

    // epilogue: gates -> cell state (regs) -> h via LDS transpose
#pragma unroll
    for (int mi = 0; mi < 2; ++mi)
#pragma unroll
      for (int rr = 0; rr < 4; ++rr) {
        const float zi = acc[mi][0][rr], zf = acc[mi][1][rr];
        const float zg = acc[mi][2][rr], zo = acc[mi][3][rr];
        const float cn = sigm(zf) * cst[mi][rr] + sigm(zi) * tanhp(zg);
        cst[mi][rr] = cn;
        epi[(w * 32 + mi * 16 + q * 4 + rr) * EPI_STR + m16] = __float2bfloat16(sigm(zo) * tanhp(cn));
      }
    __syncthreads();
    {
      const int r = tid >> 1, hf = tid & 1;
      bf16x8 hv = *(const bf16x8*)(epi + r * EPI_STR + hf * 8);
      coh_store16(hout + (size_t)(m0 + r) * HDIM + jbase + hf * 8, hv);
    }
    WAIT_VM0;                                      // each wave drains its h stores
    __syncthreads();
    if (tid == 0) flag_store(p.flags + fself * 4, s + 1);
  }
}

__global__ __launch_bounds__(256) void lstm_seq(Params p) {
  extern __shared__ char smem[];
  const int tid = threadIdx.x;
  const bool z2  = ((blockIdx.x & 1) == 0);
  const int grp  = (blockIdx.x >> 1) & 3;
  const int ntile = blockIdx.x >> 3;

  if (z2) role_loop<true>(p, smem, tid, grp, ntile);
  else    role_loop<false>(p, smem, tid, grp, ntile);

  // final FC: block b -> rows {2b, 2b+1}; wait on producing z2 group's flags
  const int lane = tid & 63, w = tid >> 6;
  if (w == 0) {
    const int g2 = blockIdx.x >> 6;
    gate_wave(p.flags, 128 + g2 * 32, TSTEPS, 128 + g2 * 32, TSTEPS, lane);
  }
  __syncthreads();
  if (w < 2) {
    const int row = blockIdx.x * 2 + w;
    const unsigned int* hp = (const unsigned int*)(p.h2b[1] + (size_t)row * HDIM);  // h2[79]
    float sum = 0.f;
#pragma unroll
    for (int cc = 0; cc < 4; ++cc) {
      unsigned int d = coh_load(hp + lane * 4 + cc);
      union { unsigned int ui; float f; } lo, hi;
      lo.ui = d << 16; hi.ui = d & 0xffff0000u;
      sum += lo.f * p.Wfc[(lane * 4 + cc) * 2] + hi.f * p.Wfc[(lane * 4 + cc) * 2 + 1];
    }
#pragma unroll
    for (int o = 32; o > 0; o >>= 1) sum += __shfl_down(sum, o, 64);
    if (lane == 0) p.out[row] = sigm(sum + p.bfc[0]);
  }
}

// ---------------- host launcher ----------------

extern "C" void kernel_launch(void* const* d_in, const int* in_sizes, int n_in,
                              void* d_out, int out_size, void* d_ws, size_t ws_size,
                              hipStream_t stream) {
  const int*   tokens = (const int*)d_in[0];
  const float* emb = (const float*)d_in[1];
  const float* W1  = (const float*)d_in[2];
  const float* U1  = (const float*)d_in[3];
  const float* b1  = (const float*)d_in[4];
  const float* W2  = (const float*)d_in[5];
  const float* U2  = (const float*)d_in[6];
  const float* b2  = (const float*)d_in[7];
  const float* Wfc = (const float*)d_in[8];
  const float* bfc = (const float*)d_in[9];

  char* ws = (char*)d_ws;
  size_t off = 0;
  auto alloc = [&](size_t bytes) {
    char* r = ws + off;
    off += (bytes + 255) & ~(size_t)255;
    return r;
  };
  __hip_bfloat16* Wz1t = (__hip_bfloat16*)alloc(2048UL * K1 * 2);
  __hip_bfloat16* Wz2t = (__hip_bfloat16*)alloc(2048UL * K2 * 2);
  float* bz1 = (float*)alloc(2048 * 4);
  float* bz2 = (float*)alloc(2048 * 4);
  __hip_bfloat16* Xall = (__hip_bfloat16*)alloc((size_t)TSTEPS * BATCH * EDIM * 2);
  // state: 3 h1 + 2 h2 buffers (5 * 512KB) + flags (256 * 16B = 4096B), ALL zeroed
  char* state = alloc(5UL * 524288 + 4096);
  Params prm;
  for (int i = 0; i < 3; ++i) prm.h1b[i] = (__hip_bfloat16*)(state + (size_t)i * 524288);
  for (int i = 0; i < 2; ++i) prm.h2b[i] = (__hip_bfloat16*)(state + 1572864 + (size_t)i * 524288);
  prm.flags = (int*)(state + 2621440);

  prep_weights<<<dim3(14352), dim3(256), 0, stream>>>(W1, U1, b1, W2, U2, b2, Wz1t, Wz2t, bz1, bz2);
  prep_gather<<<dim3(10240), dim3(256), 0, stream>>>(tokens, emb, Xall);
  zero_ws<<<dim3(642), dim3(256), 0, stream>>>((float4*)state, 164096);   // 2625536 B

  hipFuncSetAttribute((const void*)lstm_seq,
                      hipFuncAttributeMaxDynamicSharedMemorySize, LDS_BYTES);

  prm.Wz1t = Wz1t; prm.Wz2t = Wz2t; prm.bz1 = bz1; prm.bz2 = bz2;
  prm.Xall = Xall;
  prm.Wfc = Wfc; prm.bfc = bfc;
  prm.out = (float*)d_out;

  lstm_seq<<<dim3(256), dim3(256), LDS_BYTES, stream>>>(prm);
}

// Round 7
// 935.562 us; speedup vs baseline: 1.3281x; 1.1057x over previous
//
#include <hip/hip_runtime.h>
#include <hip/hip_bf16.h>

typedef __bf16  bf16x8 __attribute__((ext_vector_type(8)));
typedef float   f32x4  __attribute__((ext_vector_type(4)));

// global->LDS async, 16B/lane. _C: fully cached (immutable X stream).
// _H: sc0 = bypass L1, allocate L2 (h panels; freshness via 12-deep slot
// rotation + aligned fence every 8 phases -- see correctness note below).
#define GLOAD16_C(gptr, lptr) \
  __builtin_amdgcn_global_load_lds((const __attribute__((address_space(1))) void*)(gptr), \
                                   (__attribute__((address_space(3))) void*)(lptr), 16, 0, 0)
#define GLOAD16_H(gptr, lptr) \
  __builtin_amdgcn_global_load_lds((const __attribute__((address_space(1))) void*)(gptr), \
                                   (__attribute__((address_space(3))) void*)(lptr), 16, 0, 0x1)

#define WAIT_VM10  asm volatile("s_waitcnt vmcnt(10)" ::: "memory")
#define WAIT_VM8   asm volatile("s_waitcnt vmcnt(8)"  ::: "memory")
#define WAIT_VM6   asm volatile("s_waitcnt vmcnt(6)"  ::: "memory")
#define WAIT_VM4   asm volatile("s_waitcnt vmcnt(4)"  ::: "memory")
#define WAIT_VM2   asm volatile("s_waitcnt vmcnt(2)"  ::: "memory")
#define WAIT_VM0   asm volatile("s_waitcnt vmcnt(0)"  ::: "memory")
#define WAIT_LGKM0 asm volatile("s_waitcnt lgkmcnt(0)" ::: "memory")

__device__ __forceinline__ void wait_rem(int rem) {
  if      (rem >= 5) WAIT_VM10;
  else if (rem == 4) WAIT_VM8;
  else if (rem == 3) WAIT_VM6;
  else if (rem == 2) WAIT_VM4;
  else if (rem == 1) WAIT_VM2;
  else               WAIT_VM0;
}

__device__ __forceinline__ float sigm(float x)  { return 1.0f / (1.0f + __expf(-x)); }
__device__ __forceinline__ float tanhp(float x) { return 2.0f / (1.0f + __expf(-2.0f * x)) - 1.0f; }

// LLC-coherent scalar load / stores (bypass L1/L2)
__device__ __forceinline__ unsigned int coh_load(const unsigned int* p) {
  unsigned int v;
  asm volatile("global_load_dword %0, %1, off sc0 sc1\n\ts_waitcnt vmcnt(0)"
               : "=v"(v) : "v"(p) : "memory");
  return v;
}
__device__ __forceinline__ int coh_load_i(const int* p) {
  int v;
  asm volatile("global_load_dword %0, %1, off sc0 sc1\n\ts_waitcnt vmcnt(0)"
               : "=v"(v) : "v"(p) : "memory");
  return v;
}
__device__ __forceinline__ void coh_store16(void* p, bf16x8 v) {
  f32x4 f = *(f32x4*)&v;
  asm volatile("global_store_dwordx4 %0, %1, off sc0 sc1" :: "v"(p), "v"(f) : "memory");
}
__device__ __forceinline__ void flag_store(int* fp, int v) {
  asm volatile("global_store_dword %0, %1, off sc0 sc1" :: "v"(fp), "v"(v) : "memory");
}

#define TSTEPS 80
#define BATCH  512
#define EDIM   256
#define HDIM   512
#define K2     1024
#define K1     768
#define NCH    8            // B K-chunks held in registers
#define D_SLOTS 12
#define SLOT_BYTES 524544   // 512 KB + 256 B guard
// LDS: BsL (<=24 chunks * 4KB) | ring (6 * 8KB) | epi (128 x 24 bf16)
#define RING_OFF 98304
#define EPI_OFF  147456
#define EPI_STR  24
#define LDS_BYTES 153600

struct Params {
  const __hip_bfloat16* Wz1t;   // [2048][768]  bf16, [N'][K], K-order [W1|U1]
  const __hip_bfloat16* Wz2t;   // [2048][1024]             K-order [U2|W2]
  const float* bz1;             // [2048] permuted
  const float* bz2;
  const __hip_bfloat16* Xall;   // [80][512][256] bf16
  char* h1base;                 // 12 slots, SLOT_BYTES stride
  char* h2base;                 // 12 slots
  int* flags;                   // 256 entries, 16B stride: z1 at idx, z2 at 128+idx
  const float* Wfc; const float* bfc;
  float* out;
};

// ---------------- prep kernels ----------------
// permuted column: n' = ntile*64 + gate*16 + u  (ntile = j>>4, u = j&15)
// K-order REORDERED to put the gated h1-operand LAST:
//   Wz1t: k<256 -> W1[k] (x-part), k>=256 -> U1[k-256] (h1-part)
//   Wz2t: k<512 -> U2[k] (h2-part), k>=512 -> W2[k-512] (h1-part)

__global__ __launch_bounds__(256) void prep_weights(
    const float* __restrict__ W1, const float* __restrict__ U1, const float* __restrict__ b1,
    const float* __restrict__ W2, const float* __restrict__ U2, const float* __restrict__ b2,
    __hip_bfloat16* __restrict__ Wz1t, __hip_bfloat16* __restrict__ Wz2t,
    float* __restrict__ bz1, float* __restrict__ bz2) {
  long idx = (long)blockIdx.x * 256 + threadIdx.x;
  const long n1 = 2048L * K1, n2 = 2048L * K2;
  if (idx < n1) {
    int n = (int)(idx / K1), k = (int)(idx % K1);
    int col = ((n >> 4) & 3) * 512 + (n >> 6) * 16 + (n & 15);
    float v = (k < 256) ? W1[(size_t)k * 2048 + col] : U1[(size_t)(k - 256) * 2048 + col];
    Wz1t[idx] = __float2bfloat16(v);
  } else if (idx < n1 + n2) {
    long r = idx - n1;
    int n = (int)(r / K2), k = (int)(r % K2);
    int col = ((n >> 4) & 3) * 512 + (n >> 6) * 16 + (n & 15);
    float v = (k < 512) ? U2[(size_t)k * 2048 + col] : W2[(size_t)(k - 512) * 2048 + col];
    Wz2t[r] = __float2bfloat16(v);
  } else if (idx < n1 + n2 + 2048) {
    int n = (int)(idx - (n1 + n2));
    bz1[n] = b1[((n >> 4) & 3) * 512 + (n >> 6) * 16 + (n & 15)];
  } else if (idx < n1 + n2 + 4096) {
    int n = (int)(idx - (n1 + n2 + 2048));
    bz2[n] = b2[((n >> 4) & 3) * 512 + (n >> 6) * 16 + (n & 15)];
  }
}

__global__ __launch_bounds__(256) void prep_gather(
    const int* __restrict__ tokens, const float* __restrict__ emb,
    __hip_bfloat16* __restrict__ Xall, float4* __restrict__ zp, int zn) {
  int idx = blockIdx.x * 256 + threadIdx.x;
  if (idx < zn) zp[idx] = make_float4(0.f, 0.f, 0.f, 0.f);   // zero state+flags
  int e  = (idx & 63) * 4;
  int rb = idx >> 6;            // t*512 + b
  int t  = rb >> 9;
  int b  = rb & 511;
  int tok = tokens[b * TSTEPS + t];
  const float4 v = *(const float4*)&emb[(size_t)tok * EDIM + e];
  __hip_bfloat16* o = Xall + (size_t)rb * EDIM + e;
  o[0] = __float2bfloat16(v.x); o[1] = __float2bfloat16(v.y);
  o[2] = __float2bfloat16(v.z); o[3] = __float2bfloat16(v.w);
}

// ---------------- main kernel ----------------
// 256 blocks x 256 threads, 1 block/CU, regular launch. Block b: role z2 if
// (b&1)==0, grp=(b>>1)&3 (rows grp*128..), ntile=b>>3; blockIdx%8=2*grp+role
// puts each 32-block (grp,role) set on one XCD (perf heuristic only).
//
// COHERENCE DESIGN: h slots rotate over 12 buffers; h stores are
// write-through sc0sc1 (LLC authoritative, no dirty L2 lines anywhere), so
// any cached h line is a clean snapshot. A snapshot can only be stale when
// its ADDRESS is rewritten (every 12 phases). Peer gating bounds intra-XCD
// skew to <=1 phase, so gen-g lines are last fetched by phase ~g+2 and next
// read (gen g+12) at phase g+12; every block executes an agent-acquire fence
// at s%8==0 -> in any such window a purge happens on every XCD/CU before
// reuse. Hence NO per-phase fence, and panels are L2-served (fetched from
// LLC once per XCD instead of 32x). h loads use sc0 (L1-bypass) so only L2
// freshness matters. X/weights are immutable -> never stale.
//
// K-ORDER: ungated operand first (z2: h2[s-1]; z1: x[s]), gate, then gated
// h1 half -- hides the producer->consumer handshake behind ~1us of MFMA.

__device__ __forceinline__ void gate_wave(const int* flags, int base1, int t1,
                                          int base2, int t2, int lane) {
  const int idx = lane & 31;
  const int* fp = flags + (((lane < 32) ? base1 : base2) + idx) * 4;   // 16B stride
  const int tgt = (lane < 32) ? t1 : t2;
  for (;;) {
    int v = coh_load_i(fp);
    if (__ballot(v >= tgt) == ~0ull) break;
    __builtin_amdgcn_s_sleep(2);
  }
}

template<bool Z2>
__device__ __forceinline__ void role_loop(const Params& p, char* smem, int tid,
                                          int grp, int ntile) {
  constexpr int K   = Z2 ? K2 : K1;
  constexpr int NC  = K / 32;
  constexpr int NC1 = Z2 ? 16 : 8;       // ungated chunks (h2 / x)
  const int lane = tid & 63;
  const int w    = tid >> 6;
  const int q    = lane >> 4;
  const int m16  = lane & 15;
  const int m0   = grp * 128;
  const int n0   = ntile * 64;

  __hip_bfloat16* BsL  = (__hip_bfloat16*)smem;
  __hip_bfloat16* ring = (__hip_bfloat16*)(smem + RING_OFF);
  __hip_bfloat16* epi  = (__hip_bfloat16*)(smem + EPI_OFF);

  const __hip_bfloat16* Bg = (Z2 ? p.Wz2t : p.Wz1t) + (size_t)n0 * K;

  // one-time: B chunks 0..NCH-1 into registers (static indexing only)
  bf16x8 breg[NCH][4];
#pragma unroll
  for (int kc = 0; kc < NCH; ++kc)
#pragma unroll
    for (int g = 0; g < 4; ++g)
      breg[kc][g] = *(const bf16x8*)(Bg + (size_t)(g * 16 + m16) * K + kc * 32 + q * 8);

  // one-time: B chunks NCH..NC-1 into LDS, chunk-major granule-swizzled
  for (int it0 = tid; it0 < (NC - NCH) * 256; it0 += 256) {
    int cid = it0 >> 8, gg = it0 & 255;
    int r = gg >> 2, c8 = gg & 3;
    int sw = c8 ^ ((r >> 1) & 3);
    *(bf16x8*)(BsL + cid * 2048 + r * 32 + sw * 8) =
        *(const bf16x8*)(Bg + (size_t)r * K + (NCH + cid) * 32 + c8 * 8);
  }
  const float* bias = Z2 ? p.bz2 : p.bz1;
  float bz[4];
#pragma unroll
  for (int g = 0; g < 4; ++g) bz[g] = bias[n0 + g * 16 + m16];

  const int swz = (q ^ ((m16 >> 1) & 3)) * 8;
  int aoff[2], boff[4];
#pragma unroll
  for (int mi = 0; mi < 2; ++mi) aoff[mi] = (w * 32 + mi * 16 + m16) * 32 + swz;
#pragma unroll
  for (int g = 0; g < 4; ++g)    boff[g]  = (g * 16 + m16) * 32 + swz;

  float cst[2][4] = {{0.f,0.f,0.f,0.f},{0.f,0.f,0.f,0.f}};
  const int fself = (Z2 ? 128 : 0) + grp * 32 + ntile;
  const int jbase = ntile * 16;
  __syncthreads();

  for (int s = 0; s < TSTEPS; ++s) {
    const int sl = s % D_SLOTS, slp = (s + D_SLOTS - 1) % D_SLOTS;
    const __hip_bfloat16* Ah1 = (const __hip_bfloat16*)
        (p.h1base + (size_t)(Z2 ? sl : slp) * SLOT_BYTES);          // h1[s] / h1[s-1]
    const __hip_bfloat16* Au  = Z2
        ? (const __hip_bfloat16*)(p.h2base + (size_t)slp * SLOT_BYTES)   // h2[s-1]
        : p.Xall + (size_t)s * BATCH * EDIM;                             // x[s]
    __hip_bfloat16* hout = (__hip_bfloat16*)
        ((Z2 ? p.h2base : p.h1base) + (size_t)sl * SLOT_BYTES);

    auto stage = [&](int kc) {
      const int slot = kc % 6;
#pragma unroll
      for (int it = 0; it < 2; ++it) {
        const int gbase = w * 128 + it * 64;
        const int g   = gbase + lane;
        const int row = g >> 2;
        const int gc  = (g & 3) ^ ((row >> 1) & 3);       // XOR swizzle
        __hip_bfloat16* lp = ring + slot * 4096 + gbase * 8;
        if (kc < NC1) {
          if (Z2) GLOAD16_H(Au + (size_t)(m0 + row) * 512 + kc * 32 + gc * 8, lp);
          else    GLOAD16_C(Au + (size_t)(m0 + row) * 256 + kc * 32 + gc * 8, lp);
        } else {
          GLOAD16_H(Ah1 + (size_t)(m0 + row) * 512 + (kc - NC1) * 32 + gc * 8, lp);
        }
      }
    };

    f32x4 acc[2][4];
#pragma unroll
    for (int mi = 0; mi < 2; ++mi)
#pragma unroll
      for (int g = 0; g < 4; ++g)
        acc[mi][g] = (f32x4){bz[g], bz[g], bz[g], bz[g]};

    // ---- part 1: ungated half ----
    if (Z2) {
      if (w == 0) {
        gate_wave(p.flags, 128 + grp * 32, s, 128 + grp * 32, s, lane);   // peers done s-1
        if ((s & 7) == 0) __builtin_amdgcn_fence(__ATOMIC_ACQUIRE, "agent");
      }
      __syncthreads();
    }
#pragma unroll
    for (int k0 = 0; k0 < 6; ++k0) stage(k0);
#pragma unroll
    for (int kc = 0; kc < NC1; ++kc) {
      wait_rem(NC1 - 1 - kc);
      const int slot = kc % 6;
      bf16x8 af[2], bfr[4];
#pragma unroll
      for (int mi = 0; mi < 2; ++mi)
        af[mi] = *(const bf16x8*)(ring + slot * 4096 + aoff[mi]);
#pragma unroll
      for (int g = 0; g < 4; ++g)
        bfr[g] = (kc < NCH) ? breg[kc][g]
                            : *(const bf16x8*)(BsL + (kc - NCH) * 2048 + boff[g]);
      WAIT_LGKM0;
      if (kc + 6 < NC1) stage(kc + 6);
#pragma unroll
      for (int mi = 0; mi < 2; ++mi)
#pragma unroll
        for (int g = 0; g < 4; ++g)
          acc[mi][g] = __builtin_amdgcn_mfma_f32_16x16x32_bf16(af[mi], bfr[g], acc[mi][g], 0, 0, 0);
    }

    // ---- part 2 gate + gated h1 half ----
    if (w == 0) {
      if (Z2) gate_wave(p.flags, grp * 32, s + 1, grp * 32, s + 1, lane);
      else {  gate_wave(p.flags, grp * 32, s, 128 + grp * 32, s - (D_SLOTS - 1), lane);
              if ((s & 7) == 0) __builtin_amdgcn_fence(__ATOMIC_ACQUIRE, "agent"); }
    }
    __syncthreads();

#pragma unroll
    for (int k0 = NC1; k0 < NC1 + 6; ++k0) stage(k0);
    for (int kc = NC1; kc < NC; ++kc) {
      wait_rem(NC - 1 - kc);
      const int slot = kc % 6;
      bf16x8 af[2], bfr[4];
#pragma unroll
      for (int mi = 0; mi < 2; ++mi)
        af[mi] = *(const bf16x8*)(ring + slot * 4096 + aoff[mi]);
#pragma unroll
      for (int g = 0; g < 4; ++g)
        bfr[g] = *(const bf16x8*)(BsL + (kc - NCH) * 2048 + boff[g]);
      WAIT_LGKM0;
      if (kc + 6 < NC) stage(kc + 6);
#pragma unroll
      for (int mi = 0; mi < 2; ++mi)
#pragma unroll
        for (int g = 0; g < 4; ++g)
          acc[mi][g] = __builtin_amdgcn_mfma_f32_16x16x32_bf16(af[mi], bfr[g], acc[mi][g], 0, 0, 0);
    }

    // epilogue: gates -> cell state (regs) -> h via LDS transpose
#pragma unroll
    for (int mi = 0; mi < 2; ++mi)
#pragma unroll
      for (int rr = 0; rr < 4; ++rr) {
        const float zi = acc[mi][0][rr], zf = acc[mi][1][rr];
        const float zg = acc[mi][2][rr], zo = acc[mi][3][rr];
        const float cn = sigm(zf) * cst[mi][rr] + sigm(zi) * tanhp(zg);
        cst[mi][rr] = cn;
        epi[(w * 32 + mi * 16 + q * 4 + rr) * EPI_STR + m16] = __float2bfloat16(sigm(zo) * tanhp(cn));
      }
    __syncthreads();
    {
      const int r = tid >> 1, hf = tid & 1;
      bf16x8 hv = *(const bf16x8*)(epi + r * EPI_STR + hf * 8);
      coh_store16(hout + (size_t)(m0 + r) * HDIM + jbase + hf * 8, hv);
    }
    WAIT_VM0;                                      // h committed to LLC
    __syncthreads();
    if (tid == 0) flag_store(p.flags + fself * 4, s + 1);
  }
}

__global__ __launch_bounds__(256) void lstm_seq(Params p) {
  extern __shared__ char smem[];
  const int tid = threadIdx.x;
  const bool z2  = ((blockIdx.x & 1) == 0);
  const int grp  = (blockIdx.x >> 1) & 3;
  const int ntile = blockIdx.x >> 3;

  if (z2) role_loop<true>(p, smem, tid, grp, ntile);
  else    role_loop<false>(p, smem, tid, grp, ntile);

  // final FC: block b -> rows {2b, 2b+1}; wait on producing z2 group's flags
  const int lane = tid & 63, w = tid >> 6;
  if (w == 0) {
    const int g2 = blockIdx.x >> 6;
    gate_wave(p.flags, 128 + g2 * 32, TSTEPS, 128 + g2 * 32, TSTEPS, lane);
  }
  __syncthreads();
  if (w < 2) {
    const int row = blockIdx.x * 2 + w;
    const unsigned int* hp = (const unsigned int*)
        (p.h2base + (size_t)((TSTEPS - 1) % D_SLOTS) * SLOT_BYTES) + (size_t)row * (HDIM / 2);
    float sum = 0.f;
#pragma unroll
    for (int cc = 0; cc < 4; ++cc) {
      unsigned int d = coh_load(hp + lane * 4 + cc);
      union { unsigned int ui; float f; } lo, hi;
      lo.ui = d << 16; hi.ui = d & 0xffff0000u;
      sum += lo.f * p.Wfc[(lane * 4 + cc) * 2] + hi.f * p.Wfc[(lane * 4 + cc) * 2 + 1];
    }
#pragma unroll
    for (int o = 32; o > 0; o >>= 1) sum += __shfl_down(sum, o, 64);
    if (lane == 0) p.out[row] = sigm(sum + p.bfc[0]);
  }
}

// ---------------- host launcher ----------------

extern "C" void kernel_launch(void* const* d_in, const int* in_sizes, int n_in,
                              void* d_out, int out_size, void* d_ws, size_t ws_size,
                              hipStream_t stream) {
  const int*   tokens = (const int*)d_in[0];
  const float* emb = (const float*)d_in[1];
  const float* W1  = (const float*)d_in[2];
  const float* U1  = (const float*)d_in[3];
  const float* b1  = (const float*)d_in[4];
  const float* W2  = (const float*)d_in[5];
  const float* U2  = (const float*)d_in[6];
  const float* b2  = (const float*)d_in[7];
  const float* Wfc = (const float*)d_in[8];
  const float* bfc = (const float*)d_in[9];

  char* ws = (char*)d_ws;
  size_t off = 0;
  auto alloc = [&](size_t bytes) {
    char* r = ws + off;
    off += (bytes + 255) & ~(size_t)255;
    return r;
  };
  __hip_bfloat16* Wz1t = (__hip_bfloat16*)alloc(2048UL * K1 * 2);
  __hip_bfloat16* Wz2t = (__hip_bfloat16*)alloc(2048UL * K2 * 2);
  float* bz1 = (float*)alloc(2048 * 4);
  float* bz2 = (float*)alloc(2048 * 4);
  __hip_bfloat16* Xall = (__hip_bfloat16*)alloc((size_t)TSTEPS * BATCH * EDIM * 2);
  // state: 24 h-slots (12 h1 + 12 h2) + flags (4096B), ALL zeroed in prep_gather
  const size_t state_bytes = 24UL * SLOT_BYTES + 4096;   // 12,593,152
  char* state = alloc(state_bytes);

  Params prm;
  prm.h1base = state;
  prm.h2base = state + 12UL * SLOT_BYTES;
  prm.flags  = (int*)(state + 24UL * SLOT_BYTES);

  prep_weights<<<dim3(14352), dim3(256), 0, stream>>>(W1, U1, b1, W2, U2, b2, Wz1t, Wz2t, bz1, bz2);
  prep_gather<<<dim3(10240), dim3(256), 0, stream>>>(tokens, emb, Xall,
                                                     (float4*)state, (int)(state_bytes / 16));

  hipFuncSetAttribute((const void*)lstm_seq,
                      hipFuncAttributeMaxDynamicSharedMemorySize, LDS_BYTES);

  prm.Wz1t = Wz1t; prm.Wz2t = Wz2t; prm.bz1 = bz1; prm.bz2 = bz2;
  prm.Xall = Xall;
  prm.Wfc = Wfc; prm.bfc = bfc;
  prm.out = (float*)d_out;

  lstm_seq<<<dim3(256), dim3(256), LDS_BYTES, stream>>>(prm);
}

// Round 8
// 715.852 us; speedup vs baseline: 1.7357x; 1.3069x over previous
//
#include <hip/hip_runtime.h>
#include <hip/hip_bf16.h>

typedef __bf16  bf16x8 __attribute__((ext_vector_type(8)));
typedef float   f32x4  __attribute__((ext_vector_type(4)));

// global->LDS async, 16B/lane. _C: fully cached (immutable X stream).
// _H: sc0 = bypass L1, allocate L2 (h panels; freshness via 12-deep slot
// rotation + aligned fence every 8 phases -- proven R7).
#define GLOAD16_C(gptr, lptr) \
  __builtin_amdgcn_global_load_lds((const __attribute__((address_space(1))) void*)(gptr), \
                                   (__attribute__((address_space(3))) void*)(lptr), 16, 0, 0)
#define GLOAD16_H(gptr, lptr) \
  __builtin_amdgcn_global_load_lds((const __attribute__((address_space(1))) void*)(gptr), \
                                   (__attribute__((address_space(3))) void*)(lptr), 16, 0, 0x1)

#define WAIT_VM10  asm volatile("s_waitcnt vmcnt(10)" ::: "memory")
#define WAIT_VM8   asm volatile("s_waitcnt vmcnt(8)"  ::: "memory")
#define WAIT_VM6   asm volatile("s_waitcnt vmcnt(6)"  ::: "memory")
#define WAIT_VM4   asm volatile("s_waitcnt vmcnt(4)"  ::: "memory")
#define WAIT_VM2   asm volatile("s_waitcnt vmcnt(2)"  ::: "memory")
#define WAIT_VM0   asm volatile("s_waitcnt vmcnt(0)"  ::: "memory")

__device__ __forceinline__ void wait_vm_chunks(int n) {   // n chunks (2 vm each) may stay outstanding
  if      (n <= 0) WAIT_VM0;
  else if (n == 1) WAIT_VM2;
  else if (n == 2) WAIT_VM4;
  else if (n == 3) WAIT_VM6;
  else if (n == 4) WAIT_VM8;
  else             WAIT_VM10;
}
__device__ __forceinline__ void wait_lgkm_n(int n) {
  if      (n <= 0) asm volatile("s_waitcnt lgkmcnt(0)" ::: "memory");
  else if (n <= 2) asm volatile("s_waitcnt lgkmcnt(2)" ::: "memory");
  else             asm volatile("s_waitcnt lgkmcnt(6)" ::: "memory");
}

__device__ __forceinline__ float sigm(float x)  { return 1.0f / (1.0f + __expf(-x)); }
__device__ __forceinline__ float tanhp(float x) { return 2.0f / (1.0f + __expf(-2.0f * x)) - 1.0f; }

// LLC-coherent scalar load / stores (bypass L1/L2)
__device__ __forceinline__ unsigned int coh_load(const unsigned int* p) {
  unsigned int v;
  asm volatile("global_load_dword %0, %1, off sc0 sc1\n\ts_waitcnt vmcnt(0)"
               : "=v"(v) : "v"(p) : "memory");
  return v;
}
__device__ __forceinline__ int coh_load_i(const int* p) {
  int v;
  asm volatile("global_load_dword %0, %1, off sc0 sc1\n\ts_waitcnt vmcnt(0)"
               : "=v"(v) : "v"(p) : "memory");
  return v;
}
__device__ __forceinline__ void coh_store16(void* p, bf16x8 v) {
  f32x4 f = *(f32x4*)&v;
  asm volatile("global_store_dwordx4 %0, %1, off sc0 sc1" :: "v"(p), "v"(f) : "memory");
}
__device__ __forceinline__ void flag_store(int* fp, int v) {
  asm volatile("global_store_dword %0, %1, off sc0 sc1" :: "v"(fp), "v"(v) : "memory");
}

#define TSTEPS 80
#define BATCH  512
#define EDIM   256
#define HDIM   512
#define K2     1024
#define K1     768
#define NCH    16           // B K-chunks in registers (256 VGPR; 1 wave/SIMD -> budget 512)
#define D_SLOTS 12
#define SLOT_BYTES 524544   // 512 KB + 256 B guard
// LDS: BsL (<=16 chunks * 4KB = 64KB) | ring (8 * 8KB = 64KB) | epi (128 x 24 bf16)
#define RING_OFF 65536
#define EPI_OFF  131072
#define EPI_STR  24
#define LDS_BYTES 137216

struct Params {
  const __hip_bfloat16* Wz1t;   // [2048][768]  bf16, [N'][K], K-order [W1|U1] (x first)
  const __hip_bfloat16* Wz2t;   // [2048][1024]             K-order [W2|U2] (h1 first)
  const float* bz1;             // [2048] permuted
  const float* bz2;
  const __hip_bfloat16* Xall;   // [80][512][256] bf16
  char* h1base;                 // 12 slots, SLOT_BYTES stride
  char* h2base;                 // 12 slots
  int* flags;                   // 256 entries, 16B stride: z1 at idx, z2 at 128+idx
  const float* Wfc; const float* bfc;
  float* out;
};

// ---------------- prep kernels ----------------
// permuted column: n' = ntile*64 + gate*16 + u  (ntile = j>>4, u = j&15)
// K-order: the TIGHT-gated operand goes LAST:
//   Wz1t: k<256 -> W1[k] (x),  k>=256 -> U1[k-256] (h1[s-1], peer-gated)
//   Wz2t: k<512 -> W2[k] (h1), k>=512 -> U2[k-512] (h2[s-1], peer-gated)

__global__ __launch_bounds__(256) void prep_weights(
    const float* __restrict__ W1, const float* __restrict__ U1, const float* __restrict__ b1,
    const float* __restrict__ W2, const float* __restrict__ U2, const float* __restrict__ b2,
    __hip_bfloat16* __restrict__ Wz1t, __hip_bfloat16* __restrict__ Wz2t,
    float* __restrict__ bz1, float* __restrict__ bz2) {
  long idx = (long)blockIdx.x * 256 + threadIdx.x;
  const long n1 = 2048L * K1, n2 = 2048L * K2;
  if (idx < n1) {
    int n = (int)(idx / K1), k = (int)(idx % K1);
    int col = ((n >> 4) & 3) * 512 + (n >> 6) * 16 + (n & 15);
    float v = (k < 256) ? W1[(size_t)k * 2048 + col] : U1[(size_t)(k - 256) * 2048 + col];
    Wz1t[idx] = __float2bfloat16(v);
  } else if (idx < n1 + n2) {
    long r = idx - n1;
    int n = (int)(r / K2), k = (int)(r % K2);
    int col = ((n >> 4) & 3) * 512 + (n >> 6) * 16 + (n & 15);
    float v = (k < 512) ? W2[(size_t)k * 2048 + col] : U2[(size_t)(k - 512) * 2048 + col];
    Wz2t[r] = __float2bfloat16(v);
  } else if (idx < n1 + n2 + 2048) {
    int n = (int)(idx - (n1 + n2));
    bz1[n] = b1[((n >> 4) & 3) * 512 + (n >> 6) * 16 + (n & 15)];
  } else if (idx < n1 + n2 + 4096) {
    int n = (int)(idx - (n1 + n2 + 2048));
    bz2[n] = b2[((n >> 4) & 3) * 512 + (n >> 6) * 16 + (n & 15)];
  }
}

__global__ __launch_bounds__(256) void prep_gather(
    const int* __restrict__ tokens, const float* __restrict__ emb,
    __hip_bfloat16* __restrict__ Xall, float4* __restrict__ zp, int zn) {
  int idx = blockIdx.x * 256 + threadIdx.x;
  if (idx < zn) zp[idx] = make_float4(0.f, 0.f, 0.f, 0.f);   // zero state+flags
  int e  = (idx & 63) * 4;
  int rb = idx >> 6;            // t*512 + b
  int t  = rb >> 9;
  int b  = rb & 511;
  int tok = tokens[b * TSTEPS + t];
  const float4 v = *(const float4*)&emb[(size_t)tok * EDIM + e];
  __hip_bfloat16* o = Xall + (size_t)rb * EDIM + e;
  o[0] = __float2bfloat16(v.x); o[1] = __float2bfloat16(v.y);
  o[2] = __float2bfloat16(v.z); o[3] = __float2bfloat16(v.w);
}

// ---------------- main kernel ----------------
// 256 blocks x 256 threads, 1 block/CU (1 wave/SIMD -> latency hidden by ILP:
// ring depth 8 > lookahead 6 kills the per-iteration lgkmcnt(0); fragments are
// register double-buffered so ds_read latency overlaps MFMA).
// Coherence scheme unchanged from R7 (12-slot rotation, write-through sc0sc1
// stores, agent-acquire fence every 8 phases at the tight gate).
// Dependency order: the tight-gated operand is computed SECOND each phase so
// the peer handshake overlaps part-A MFMA. z1 free-runs (WAR-bound only).

__device__ __forceinline__ void gate_wave(const int* flags, int base1, int t1,
                                          int base2, int t2, int lane) {
  const int idx = lane & 31;
  const int* fp = flags + (((lane < 32) ? base1 : base2) + idx) * 4;   // 16B stride
  const int tgt = (lane < 32) ? t1 : t2;
  for (;;) {
    int v = coh_load_i(fp);
    if (__ballot(v >= tgt) == ~0ull) break;
    __builtin_amdgcn_s_sleep(2);
  }
}

template<int K0, int LEN, int STRIDE, bool COH>
__device__ __forceinline__ void run_part(
    const __hip_bfloat16* __restrict__ Asrc, int m0, int w, int lane,
    __hip_bfloat16* __restrict__ ring, const __hip_bfloat16* __restrict__ BsL,
    const bf16x8 (&breg)[NCH][4], const int (&aoff)[2], const int (&boff)[4],
    f32x4 (&acc)[2][4]) {
  auto stage = [&](int kc) {
#pragma unroll
    for (int it = 0; it < 2; ++it) {
      const int gbase = w * 128 + it * 64;
      const int g   = gbase + lane;
      const int row = g >> 2;
      const int gc  = (g & 3) ^ ((row >> 1) & 3);       // XOR swizzle
      __hip_bfloat16* lp = ring + (kc & 7) * 4096 + gbase * 8;
      const __hip_bfloat16* gp = Asrc + (size_t)(m0 + row) * STRIDE + (kc - K0) * 32 + gc * 8;
      if (COH) GLOAD16_H(gp, lp); else GLOAD16_C(gp, lp);
    }
  };
#pragma unroll
  for (int f = 0; f < 6; ++f) stage(K0 + f);            // fill (LEN >= 8 always)

  bf16x8 af[2][2], bf[2][4];
  wait_vm_chunks(5);                                    // chunk K0 resident
#pragma unroll
  for (int mi = 0; mi < 2; ++mi)
    af[0][mi] = *(const bf16x8*)(ring + (K0 & 7) * 4096 + aoff[mi]);
  if (K0 >= NCH)
#pragma unroll
    for (int g = 0; g < 4; ++g)
      bf[0][g] = *(const bf16x8*)(BsL + (K0 - NCH) * 2048 + boff[g]);

#pragma unroll
  for (int i = 0; i < LEN; ++i) {
    const int kc  = K0 + i;
    const int cur = i & 1, nxt = cur ^ 1;
    if (i + 1 < LEN) {
      wait_vm_chunks(LEN - 2 - i < 4 ? LEN - 2 - i : 4);   // chunk kc+1 resident
      const int kn = kc + 1;
#pragma unroll
      for (int mi = 0; mi < 2; ++mi)
        af[nxt][mi] = *(const bf16x8*)(ring + (kn & 7) * 4096 + aoff[mi]);
      if (kn >= NCH) {
#pragma unroll
        for (int g = 0; g < 4; ++g)
          bf[nxt][g] = *(const bf16x8*)(BsL + (kn - NCH) * 2048 + boff[g]);
        wait_lgkm_n(6);                 // frags of kc done; kc+1's 6 in flight
      } else {
        wait_lgkm_n(2);
      }
      if (i + 6 < LEN) stage(kc + 6);   // slot (kc+6)&7: read 2 iters ago -> free
    } else {
      wait_lgkm_n(0);
    }
#pragma unroll
    for (int mi = 0; mi < 2; ++mi)
#pragma unroll
      for (int g = 0; g < 4; ++g)
        acc[mi][g] = __builtin_amdgcn_mfma_f32_16x16x32_bf16(
            af[cur][mi], (kc < NCH ? breg[kc][g] : bf[cur][g]), acc[mi][g], 0, 0, 0);
  }
}

template<bool Z2>
__device__ __forceinline__ void role_loop(const Params& p, char* smem, int tid,
                                          int grp, int ntile) {
  constexpr int K   = Z2 ? K2 : K1;
  constexpr int NC  = K / 32;
  constexpr int NCA = Z2 ? 16 : 8;       // part-A chunks (h1 / x)
  const int lane = tid & 63;
  const int w    = tid >> 6;
  const int q    = lane >> 4;
  const int m16  = lane & 15;
  const int m0   = grp * 128;
  const int n0   = ntile * 64;

  __hip_bfloat16* BsL  = (__hip_bfloat16*)smem;
  __hip_bfloat16* ring = (__hip_bfloat16*)(smem + RING_OFF);
  __hip_bfloat16* epi  = (__hip_bfloat16*)(smem + EPI_OFF);

  const __hip_bfloat16* Bg = (Z2 ? p.Wz2t : p.Wz1t) + (size_t)n0 * K;

  // one-time: B chunks 0..NCH-1 into registers (static indexing only)
  bf16x8 breg[NCH][4];
#pragma unroll
  for (int kc = 0; kc < NCH; ++kc)
#pragma unroll
    for (int g = 0; g < 4; ++g)
      breg[kc][g] = *(const bf16x8*)(Bg + (size_t)(g * 16 + m16) * K + kc * 32 + q * 8);

  // one-time: B chunks NCH..NC-1 into LDS, chunk-major granule-swizzled
  for (int it0 = tid; it0 < (NC - NCH) * 256; it0 += 256) {
    int cid = it0 >> 8, gg = it0 & 255;
    int r = gg >> 2, c8 = gg & 3;
    int sw = c8 ^ ((r >> 1) & 3);
    *(bf16x8*)(BsL + cid * 2048 + r * 32 + sw * 8) =
        *(const bf16x8*)(Bg + (size_t)r * K + (NCH + cid) * 32 + c8 * 8);
  }
  const float* bias = Z2 ? p.bz2 : p.bz1;
  float bz[4];
#pragma unroll
  for (int g = 0; g < 4; ++g) bz[g] = bias[n0 + g * 16 + m16];

  const int swz = (q ^ ((m16 >> 1) & 3)) * 8;
  int aoff[2], boff[4];
#pragma unroll
  for (int mi = 0; mi < 2; ++mi) aoff[mi] = (w * 32 + mi * 16 + m16) * 32 + swz;
#pragma unroll
  for (int g = 0; g < 4; ++g)    boff[g]  = (g * 16 + m16) * 32 + swz;

  float cst[2][4] = {{0.f,0.f,0.f,0.f},{0.f,0.f,0.f,0.f}};
  const int fself = (Z2 ? 128 : 0) + grp * 32 + ntile;
  const int jbase = ntile * 16;
  __syncthreads();

  for (int s = 0; s < TSTEPS; ++s) {
    const int sl = s % D_SLOTS, slp = (s + D_SLOTS - 1) % D_SLOTS;
    const __hip_bfloat16* Aa = Z2
        ? (const __hip_bfloat16*)(p.h1base + (size_t)sl * SLOT_BYTES)    // h1[s]
        : p.Xall + (size_t)s * BATCH * EDIM;                             // x[s]
    const __hip_bfloat16* Ab = Z2
        ? (const __hip_bfloat16*)(p.h2base + (size_t)slp * SLOT_BYTES)   // h2[s-1]
        : (const __hip_bfloat16*)(p.h1base + (size_t)slp * SLOT_BYTES);  // h1[s-1]
    __hip_bfloat16* hout = (__hip_bfloat16*)
        ((Z2 ? p.h2base : p.h1base) + (size_t)sl * SLOT_BYTES);

    f32x4 acc[2][4];
#pragma unroll
    for (int mi = 0; mi < 2; ++mi)
#pragma unroll
      for (int g = 0; g < 4; ++g)
        acc[mi][g] = (f32x4){bz[g], bz[g], bz[g], bz[g]};

    // ---- part A (gate: z2 needs z1 >= s+1; z1 ungated) ----
    if (Z2) {
      if (w == 0) gate_wave(p.flags, grp * 32, s + 1, grp * 32, s + 1, lane);
      __syncthreads();
    }
    if (Z2) run_part<0, 16, 512, true >(Aa, m0, w, lane, ring, BsL, breg, aoff, boff, acc);
    else    run_part<0,  8, 256, false>(Aa, m0, w, lane, ring, BsL, breg, aoff, boff, acc);

    // ---- part B gate (tight peer RAW) + periodic acquire fence ----
    if (w == 0) {
      if (Z2) gate_wave(p.flags, 128 + grp * 32, s, 128 + grp * 32, s, lane);
      else    gate_wave(p.flags, grp * 32, s, 128 + grp * 32, s - (D_SLOTS - 1), lane);
      if ((s & 7) == 0) __builtin_amdgcn_fence(__ATOMIC_ACQUIRE, "agent");
    }
    __syncthreads();
    if (Z2) run_part<16, 16, 512, true>(Ab, m0, w, lane, ring, BsL, breg, aoff, boff, acc);
    else    run_part< 8, 16, 512, true>(Ab, m0, w, lane, ring, BsL, breg, aoff, boff, acc);

    // epilogue: gates -> cell state (regs) -> h via LDS transpose
#pragma unroll
    for (int mi = 0; mi < 2; ++mi)
#pragma unroll
      for (int rr = 0; rr < 4; ++rr) {
        const float zi = acc[mi][0][rr], zf = acc[mi][1][rr];
        const float zg = acc[mi][2][rr], zo = acc[mi][3][rr];
        const float cn = sigm(zf) * cst[mi][rr] + sigm(zi) * tanhp(zg);
        cst[mi][rr] = cn;
        epi[(w * 32 + mi * 16 + q * 4 + rr) * EPI_STR + m16] = __float2bfloat16(sigm(zo) * tanhp(cn));
      }
    __syncthreads();
    {
      const int r = tid >> 1, hf = tid & 1;
      bf16x8 hv = *(const bf16x8*)(epi + r * EPI_STR + hf * 8);
      coh_store16(hout + (size_t)(m0 + r) * HDIM + jbase + hf * 8, hv);
    }
    WAIT_VM0;                                      // h committed to LLC
    __syncthreads();
    if (tid == 0) flag_store(p.flags + fself * 4, s + 1);
  }
}

__global__ __launch_bounds__(256, 1) void lstm_seq(Params p) {
  extern __shared__ char smem[];
  const int tid = threadIdx.x;
  const bool z2  = ((blockIdx.x & 1) == 0);
  const int grp  = (blockIdx.x >> 1) & 3;
  const int ntile = blockIdx.x >> 3;

  if (z2) role_loop<true>(p, smem, tid, grp, ntile);
  else    role_loop<false>(p, smem, tid, grp, ntile);

  // final FC: block b -> rows {2b, 2b+1}; wait on producing z2 group's flags
  const int lane = tid & 63, w = tid >> 6;
  if (w == 0) {
    const int g2 = blockIdx.x >> 6;
    gate_wave(p.flags, 128 + g2 * 32, TSTEPS, 128 + g2 * 32, TSTEPS, lane);
  }
  __syncthreads();
  if (w < 2) {
    const int row = blockIdx.x * 2 + w;
    const unsigned int* hp = (const unsigned int*)
        (p.h2base + (size_t)((TSTEPS - 1) % D_SLOTS) * SLOT_BYTES) + (size_t)row * (HDIM / 2);
    float sum = 0.f;
#pragma unroll
    for (int cc = 0; cc < 4; ++cc) {
      unsigned int d = coh_load(hp + lane * 4 + cc);
      union { unsigned int ui; float f; } lo, hi;
      lo.ui = d << 16; hi.ui = d & 0xffff0000u;
      sum += lo.f * p.Wfc[(lane * 4 + cc) * 2] + hi.f * p.Wfc[(lane * 4 + cc) * 2 + 1];
    }
#pragma unroll
    for (int o = 32; o > 0; o >>= 1) sum += __shfl_down(sum, o, 64);
    if (lane == 0) p.out[row] = sigm(sum + p.bfc[0]);
  }
}

// ---------------- host launcher ----------------

extern "C" void kernel_launch(void* const* d_in, const int* in_sizes, int n_in,
                              void* d_out, int out_size, void* d_ws, size_t ws_size,
                              hipStream_t stream) {
  const int*   tokens = (const int*)d_in[0];
  const float* emb = (const float*)d_in[1];
  const float* W1  = (const float*)d_in[2];
  const float* U1  = (const float*)d_in[3];
  const float* b1  = (const float*)d_in[4];
  const float* W2  = (const float*)d_in[5];
  const float* U2  = (const float*)d_in[6];
  const float* b2  = (const float*)d_in[7];
  const float* Wfc = (const float*)d_in[8];
  const float* bfc = (const float*)d_in[9];

  char* ws = (char*)d_ws;
  size_t off = 0;
  auto alloc = [&](size_t bytes) {
    char* r = ws + off;
    off += (bytes + 255) & ~(size_t)255;
    return r;
  };
  __hip_bfloat16* Wz1t = (__hip_bfloat16*)alloc(2048UL * K1 * 2);
  __hip_bfloat16* Wz2t = (__hip_bfloat16*)alloc(2048UL * K2 * 2);
  float* bz1 = (float*)alloc(2048 * 4);
  float* bz2 = (float*)alloc(2048 * 4);
  __hip_bfloat16* Xall = (__hip_bfloat16*)alloc((size_t)TSTEPS * BATCH * EDIM * 2);
  // state: 24 h-slots (12 h1 + 12 h2) + flags (4096B), ALL zeroed in prep_gather
  const size_t state_bytes = 24UL * SLOT_BYTES + 4096;   // 12,593,152
  char* state = alloc(state_bytes);

  Params prm;
  prm.h1base = state;
  prm.h2base = state + 12UL * SLOT_BYTES;
  prm.flags  = (int*)(state + 24UL * SLOT_BYTES);

  prep_weights<<<dim3(14352), dim3(256), 0, stream>>>(W1, U1, b1, W2, U2, b2, Wz1t, Wz2t, bz1, bz2);
  prep_gather<<<dim3(10240), dim3(256), 0, stream>>>(tokens, emb, Xall,
                                                     (float4*)state, (int)(state_bytes / 16));

  hipFuncSetAttribute((const void*)lstm_seq,
                      hipFuncAttributeMaxDynamicSharedMemorySize, LDS_BYTES);

  prm.Wz1t = Wz1t; prm.Wz2t = Wz2t; prm.bz1 = bz1; prm.bz2 = bz2;
  prm.Xall = Xall;
  prm.Wfc = Wfc; prm.bfc = bfc;
  prm.out = (float*)d_out;

  lstm_seq<<<dim3(256), dim3(256), LDS_BYTES, stream>>>(prm);
}